// Round 1
// baseline (161.031 us; speedup 1.0000x reference)
//
#include <hip/hip_runtime.h>
#include <math.h>

#define BATCH 16
#define CH 256
#define IH 128
#define IW 128
#define IHW (IH*IW)
#define KK 7
#define KK2 49
#define NCH 147      // conv output channels (3*49)
#define KDIM 98      // 2 ch * 49 taps
#define ASTR 132     // om LDS row stride in u16 (264B; dword stride 66 == 2 mod 32 -> <=2-way on b64 writes)
#define NROWS 9      // staged img rows h-4..h+4
#define PSTR 137     // P row stride (u32)

typedef __bf16 bf16x8 __attribute__((ext_vector_type(8)));
typedef float f32x4 __attribute__((ext_vector_type(4)));

__device__ __forceinline__ float sigmoidf_(float x){ return 1.0f/(1.0f+__expf(-x)); }
__device__ __forceinline__ unsigned short f2bf(float f){
    union{float f; unsigned u;} v; v.f=f;
    unsigned r = v.u + 0x7FFFu + ((v.u>>16)&1u);
    return (unsigned short)(r>>16);
}
__device__ __forceinline__ float bf2f(unsigned short u){
    union{unsigned u; float f;} v; v.u = ((unsigned)u)<<16; return v.f;
}

// ---------------- BN block-reduce helper ----------------
__device__ __forceinline__ void blockReduce2(float& s, float& q){
    #pragma unroll
    for (int o=32;o>0;o>>=1){ s += __shfl_down(s,o); q += __shfl_down(q,o); }
    __shared__ float ls[8], lq[8];
    int wid  = threadIdx.x >> 6;
    int lane = threadIdx.x & 63;
    if (lane==0){ ls[wid]=s; lq[wid]=q; }
    __syncthreads();
    if (threadIdx.x==0){
        int nw = blockDim.x >> 6;
        s = ls[0]; q = lq[0];
        for (int i=1;i<nw;++i){ s+=ls[i]; q+=lq[i]; }
    }
}

// ---------------- K_pre: fused channel mean+max reduce (blocks<1024) + weight pack (blocks>=1024) ----
// New B-fragment k' mapping: k' = m*8 + j; m=0..13: ky=m>>1, kx=4*(m&1)+(j>>1), c=j&1.
// kx==7 slots and m>=14 (k'>=112) are ZERO in B (A supplies garbage there, product 0).
// Bias is NOT in the GEMM (added in f32 in phase 3 of k_dcn_fused).
__global__ __launch_bounds__(256) void k_pre(const float* __restrict__ x, float* __restrict__ xc,
                                             const float* __restrict__ w_off,
                                             unsigned short* __restrict__ bw,
                                             unsigned* __restrict__ cnt){
    __shared__ float4 ls[4][64];
    __shared__ float4 lm[4][64];
    if (blockIdx.x >= 1024){
        int e = (blockIdx.x-1024)*256 + threadIdx.x;   // 20480 elements
        if (e==0) cnt[0]=0u;
        int j    = e & 7;
        int lane = (e >> 3) & 63;
        int fs   = e >> 9;                              // 0..39
        int ks   = fs & 3;
        int nt   = fs >> 2;
        int o  = nt*16 + (lane & 15);
        int kk = ks*32 + (lane >> 4)*8 + j;
        int m  = kk >> 3;
        int jj = kk & 7;
        float v = 0.f;
        if (o < NCH && m < 14){
            int ky = m >> 1;
            int kx = 4*(m&1) + (jj>>1);
            int c  = jj & 1;
            if (kx < KK) v = w_off[(size_t)o*KDIM + c*KK2 + ky*KK + kx];
        }
        bw[e] = f2bf(v);
        return;
    }
    const int tid = threadIdx.x;
    const int li = tid & 63;
    const int cq = tid >> 6;
    const int item = blockIdx.x*64 + li;
    const int b = item >> 12;
    const int hw4 = item & 4095;
    const float4* px = reinterpret_cast<const float4*>(x + (size_t)b*CH*IHW) + hw4;
    float4 s = {0.f,0.f,0.f,0.f};
    float4 m = {-3e38f,-3e38f,-3e38f,-3e38f};
    #pragma unroll 8
    for (int c=cq*64; c<cq*64+64; ++c){
        float4 v = px[(size_t)c*(IHW/4)];
        s.x+=v.x; s.y+=v.y; s.z+=v.z; s.w+=v.w;
        m.x=fmaxf(m.x,v.x); m.y=fmaxf(m.y,v.y); m.z=fmaxf(m.z,v.z); m.w=fmaxf(m.w,v.w);
    }
    ls[cq][li]=s; lm[cq][li]=m;
    __syncthreads();
    if (cq==0){
        #pragma unroll
        for (int q=1;q<4;++q){
            float4 s2 = ls[q][li], m2 = lm[q][li];
            s.x+=s2.x; s.y+=s2.y; s.z+=s2.z; s.w+=s2.w;
            m.x=fmaxf(m.x,m2.x); m.y=fmaxf(m.y,m2.y); m.z=fmaxf(m.z,m2.z); m.w=fmaxf(m.w,m2.w);
        }
        const float inv = 1.0f/(float)CH;
        float4 a = {s.x*inv, s.y*inv, s.z*inv, s.w*inv};
        float4* pxc = reinterpret_cast<float4*>(xc + (size_t)b*2*IHW) + hw4;
        pxc[0]     = a;
        pxc[IHW/4] = m;
    }
}

// ---------------- K2: fused MFMA conv + deformable sampling + BN stats (last-block) -----------
// One block = one image row (b,h). A-fragments built on the fly from packed row buffer P
// (no im2col materialization). om[147][ASTR] holds conv+bias (offsets) / sigmoid(conv+bias) (masks).
__global__ __launch_bounds__(256,3) void k_dcn_fused(const float* __restrict__ xc,
    const unsigned short* __restrict__ bw, const float* __restrict__ b_off,
    const float* __restrict__ w_dcn, float* __restrict__ outp, float* __restrict__ partial,
    float* __restrict__ stats, unsigned* __restrict__ cnt)
{
    __shared__ __align__(16) unsigned char smem[52380];
    unsigned short* om = (unsigned short*)smem;          // [147][ASTR] u16 = 38808 B
    float* imgT = (float*)(smem + 38816);                // [2][9][128] f32 = 9216 B
    unsigned* P = (unsigned*)(smem + 48032);             // [7][PSTR] u32 = 3836 B (packed bf16 c0|c1)
    float* psum = (float*)(smem + 51868);                // [128] f32
    __shared__ unsigned lastf;

    const int tid = threadIdx.x;
    const int bh = blockIdx.x;
    const int b  = bh >> 7;
    const int h  = bh & 127;
    const float* img = xc + (size_t)b*2*IHW;

    // phase 0a: stage 9 rows x 2 ch of xc into LDS (zero-filled outside image)
    for (int t = tid; t < 2*NROWS*32; t += 256){   // 576 float4 items
        int c   = t / (NROWS*32);
        int rem = t - c*(NROWS*32);
        int r   = rem >> 5;
        int x4  = rem & 31;
        int yy  = h - 4 + r;
        float4 v = {0.f,0.f,0.f,0.f};
        if ((unsigned)yy < (unsigned)IH)
            v = *reinterpret_cast<const float4*>(img + c*IHW + yy*IW + x4*4);
        *reinterpret_cast<float4*>(imgT + c*(NROWS*IW) + r*IW + x4*4) = v;
    }
    // phase 0b: packed conv-row buffer P[ky][p], p = x+3, x in [-3..131], rows h-3..h+3.
    // entry = bf16(c0) | bf16(c1)<<16, zero outside image. Built straight from global (L2-hot).
    for (int t = tid; t < 7*135; t += 256){
        int ky = t / 135;
        int p  = t - ky*135;
        int xx = p - 3;
        int yy = h - 3 + ky;
        unsigned pk = 0u;
        if (((unsigned)xx < (unsigned)IW) & ((unsigned)yy < (unsigned)IH)){
            int idx = yy*IW + xx;
            pk = (unsigned)f2bf(img[idx]) | ((unsigned)f2bf(img[IHW + idx]) << 16);
        }
        P[ky*PSTR + p] = pk;
    }
    __syncthreads();

    // phase 2: MFMA. A-fragment for frag index m = ks*4 + (lane>>4) is 4 contiguous u32 from
    // P[ky= m>>1][pix + 4*(m&1) ...]; m=14,15 read clamped row (B is zero there).
    const int wid  = tid >> 6;
    const int lane = tid & 63;
    const int l15  = lane & 15;
    const int lg   = lane >> 4;

    bf16x8 af[4][2];
    #pragma unroll
    for (int ks=0; ks<4; ++ks){
        const int m = ks*4 + lg;
        int ky = m >> 1; ky = (ky > 6) ? 6 : ky;
        const int p0 = 4*(m & 1);
        #pragma unroll
        for (int mt=0; mt<2; ++mt){
            const int pix = wid*32 + mt*16 + l15;
            const unsigned* sp = P + ky*PSTR + pix + p0;
            union { unsigned u[4]; bf16x8 v; } uu;
            uu.u[0]=sp[0]; uu.u[1]=sp[1]; uu.u[2]=sp[2]; uu.u[3]=sp[3];
            af[ks][mt] = uu.v;
        }
    }

    f32x4 acc[2][10];
    #pragma unroll
    for (int i=0;i<2;++i)
        #pragma unroll
        for (int j=0;j<10;++j) acc[i][j] = (f32x4){0.f,0.f,0.f,0.f};

    const bf16x8* bv = reinterpret_cast<const bf16x8*>(bw);
    #pragma unroll
    for (int nt=0; nt<10; ++nt){           // nt-outer: B streamed linearly, L1 temporal reuse
        #pragma unroll
        for (int ks=0; ks<4; ++ks){
            bf16x8 bfr = bv[(nt*4+ks)*64 + lane];
            acc[0][nt] = __builtin_amdgcn_mfma_f32_16x16x32_bf16(af[ks][0], bfr, acc[0][nt], 0,0,0);
            acc[1][nt] = __builtin_amdgcn_mfma_f32_16x16x32_bf16(af[ks][1], bfr, acc[1][nt], 0,0,0);
        }
    }
    // no barrier needed: om region untouched so far, P/imgT not written below

    // phase 3: bias add (+ sigmoid for mask channels), write om transposed, b64-vectorized
    #pragma unroll
    for (int nt=0; nt<10; ++nt){
        const int cn = nt*16 + l15;
        if (cn < NCH){
            const float bo = b_off[cn];
            #pragma unroll
            for (int mt=0; mt<2; ++mt){
                const int pixb = wid*32 + mt*16 + lg*4;
                ushort4 wv;
                #pragma unroll
                for (int r=0; r<4; ++r){
                    float v = acc[mt][nt][r] + bo;
                    if (cn >= KDIM) v = sigmoidf_(v);
                    reinterpret_cast<unsigned short*>(&wv)[r] = f2bf(v);
                }
                *reinterpret_cast<ushort4*>(om + cn*ASTR + pixb) = wv;
            }
        }
    }
    __syncthreads();

    // phase 4: deformable sampling from LDS tile; 2 threads/pixel split taps
    const int pix  = tid & 127;
    const int half = tid >> 7;
    const int k0 = half ? 25 : 0;
    const int k1 = half ? 49 : 25;
    const float pixf = (float)pix;
    const unsigned short* omp = om + pix;
    int   kx    = half ? 4 : 0;
    float kyloc = half ? 4.f : 1.f;        // local row (tile base h-4): ky+1
    float kxm3  = (float)(kx - 3);
    int offO = 2*k0*ASTR;
    int offM = (KDIM + k0)*ASTR;
    float accv = 0.f;
    for (int k=k0; k<k1; ++k){
        float oy  = bf2f(omp[offO]);
        float ox  = bf2f(omp[offO + ASTR]);
        float msk = bf2f(omp[offM]);
        float yl = kyloc + oy;
        float xf = pixf + (kxm3 + ox);
        float y0f = floorf(yl), x0f = floorf(xf);
        float dy = yl - y0f, dx = xf - x0f;
        int t0 = (int)y0f, x0 = (int)x0f;
        int x1 = x0 + 1;
        float fx0 = ((unsigned)x0 < (unsigned)IW) ? 1.f : 0.f;
        float fx1 = ((unsigned)x1 < (unsigned)IW) ? 1.f : 0.f;
        int xc0 = min(max(x0,0),IW-1), xc1 = min(max(x1,0),IW-1);
        float w00=(1.f-dy)*(1.f-dx)*fx0;
        float w01=(1.f-dy)*dx      *fx1;
        float w10=dy*(1.f-dx)      *fx0;
        float w11=dy*dx            *fx1;
        float s0, s1;
        if ((unsigned)t0 < 8u){                  // both rows staged (zero-filled handles y-OOB)
            const float* q0 = imgT + t0*IW;
            const float* q1 = imgT + NROWS*IW + t0*IW;
            s0 = q0[xc0]*w00 + q0[xc1]*w01 + q0[IW+xc0]*w10 + q0[IW+xc1]*w11;
            s1 = q1[xc0]*w00 + q1[xc1]*w01 + q1[IW+xc0]*w10 + q1[IW+xc1]*w11;
        } else {                                 // rare: |oy| > ~4
            int y0g = t0 + h - 4;
            int y1g = y0g + 1;
            float fy0 = ((unsigned)y0g < (unsigned)IH) ? 1.f : 0.f;
            float fy1 = ((unsigned)y1g < (unsigned)IH) ? 1.f : 0.f;
            int yc0 = min(max(y0g,0),IH-1), yc1 = min(max(y1g,0),IH-1);
            int i00 = yc0*IW+xc0, i01 = yc0*IW+xc1, i10 = yc1*IW+xc0, i11 = yc1*IW+xc1;
            s0 = img[i00]*w00*fy0 + img[i01]*w01*fy0 + img[i10]*w10*fy1 + img[i11]*w11*fy1;
            s1 = img[IHW+i00]*w00*fy0 + img[IHW+i01]*w01*fy0 + img[IHW+i10]*w10*fy1 + img[IHW+i11]*w11*fy1;
        }
        accv += msk * (s0*w_dcn[k] + s1*w_dcn[KK2+k]);
        offO += 2*ASTR; offM += ASTR;
        ++kx; kxm3 += 1.f;
        if (kx == KK){ kx = 0; kxm3 = -3.f; kyloc += 1.f; }
    }
    if (half) psum[pix] = accv;
    __syncthreads();
    float o = 0.f;
    if (!half){ o = accv + psum[pix]; outp[bh*IW + pix] = o; }
    float s = o, q = o*o;
    blockReduce2(s,q);
    if (tid==0){
        partial[bh] = s; partial[2048+bh] = q;
        __threadfence();
        unsigned old = atomicAdd(cnt, 1u);
        lastf = (old == 2047u) ? 1u : 0u;
    }
    __syncthreads();
    if (lastf){
        const volatile float* vp = partial;
        float s2 = 0.f, q2 = 0.f;
        for (int i=tid; i<2048; i+=256){ s2 += vp[i]; q2 += vp[2048+i]; }
        blockReduce2(s2,q2);
        if (tid==0){
            const float N = (float)(BATCH*IHW);
            float mean = s2/N;
            float var  = fmaxf(q2/N - mean*mean, 0.f);
            stats[0] = mean;
            stats[1] = rsqrtf(var + 1e-5f);
        }
    }
}

__global__ __launch_bounds__(256) void k_final(const float* __restrict__ outp, const float* __restrict__ stats,
    const float* __restrict__ gamma, const float* __restrict__ beta, float* __restrict__ out){
    int t = blockIdx.x*256 + threadIdx.x;
    float mean = stats[0], istd = stats[1];
    float g = gamma[0], bt = beta[0];
    float4 v = reinterpret_cast<const float4*>(outp)[t];
    float4 r;
    r.x = sigmoidf_((v.x-mean)*istd*g + bt);
    r.y = sigmoidf_((v.y-mean)*istd*g + bt);
    r.z = sigmoidf_((v.z-mean)*istd*g + bt);
    r.w = sigmoidf_((v.w-mean)*istd*g + bt);
    reinterpret_cast<float4*>(out)[t] = r;
}

extern "C" void kernel_launch(void* const* d_in, const int* in_sizes, int n_in,
                              void* d_out, int out_size, void* d_ws, size_t ws_size,
                              hipStream_t stream){
    const float* x     = (const float*)d_in[0];
    const float* w_off = (const float*)d_in[1];
    const float* b_off = (const float*)d_in[2];
    const float* w_dcn = (const float*)d_in[3];
    const float* gamma = (const float*)d_in[4];
    const float* beta  = (const float*)d_in[5];
    float* ws = (float*)d_ws;
    float* xc      = ws;                                  // 524288 f32 (2 MB)
    float* outp    = ws + 524288;                         // 262144 f32 (1 MB)
    float* partial = ws + 786432;                         // 4096 f32 (sum | sumsq)
    float* stats   = partial + 4096;                      // 2 f32 @ ws+790528
    unsigned* cnt  = (unsigned*)(ws + 790532);            // 1 u32
    unsigned short* bw = (unsigned short*)(ws + 790544);  // 20480 u16 packed weights

    hipLaunchKernelGGL(k_pre,      dim3(1104), dim3(256), 0, stream, x, xc, w_off, bw, cnt);
    hipLaunchKernelGGL(k_dcn_fused,dim3(2048), dim3(256), 0, stream, xc, bw, b_off, w_dcn, outp, partial, stats, cnt);
    hipLaunchKernelGGL(k_final,    dim3(256),  dim3(256), 0, stream, outp, stats, gamma, beta, (float*)d_out);
}

// Round 2
// 116.227 us; speedup vs baseline: 1.3855x; 1.3855x over previous
//
#include <hip/hip_runtime.h>
#include <math.h>

#define BATCH 16
#define CH 256
#define IH 128
#define IW 128
#define IHW (IH*IW)
#define KK 7
#define KK2 49
#define NCH 147      // conv output channels (3*49)
#define KDIM 98      // 2 ch * 49 taps
#define ASTR 132     // om LDS row stride in u16 (264B)
#define NROWS 9      // staged img rows h-4..h+4
#define PSTR 137     // P row stride (u32)

typedef __bf16 bf16x8 __attribute__((ext_vector_type(8)));
typedef float f32x4 __attribute__((ext_vector_type(4)));

__device__ __forceinline__ float sigmoidf_(float x){ return 1.0f/(1.0f+__expf(-x)); }
__device__ __forceinline__ unsigned short f2bf(float f){
    union{float f; unsigned u;} v; v.f=f;
    unsigned r = v.u + 0x7FFFu + ((v.u>>16)&1u);
    return (unsigned short)(r>>16);
}
__device__ __forceinline__ float bf2f(unsigned short u){
    union{unsigned u; float f;} v; v.u = ((unsigned)u)<<16; return v.f;
}

// ---------------- K0: pack weights into MFMA B-fragment order (bf16) ----------------
// k' = m*8 + j; m = ks*4 + (lane>>4), m=0..13: ky=m>>1, kx=4*(m&1)+(j>>1), c=j&1.
// kx==7 slots and m>=14 are ZERO (A supplies garbage there, product 0). No bias column.
__global__ __launch_bounds__(256) void k_pack(const float* __restrict__ w_off,
                                              unsigned short* __restrict__ bw){
    int e = blockIdx.x*256 + threadIdx.x;      // 20480 elements
    int j    = e & 7;
    int lane = (e >> 3) & 63;
    int fs   = e >> 9;                          // 0..39
    int ks   = fs & 3;
    int nt   = fs >> 2;
    int o  = nt*16 + (lane & 15);
    int m  = ks*4 + (lane >> 4);
    float v = 0.f;
    if (o < NCH && m < 14){
        int ky = m >> 1;
        int kx = 4*(m&1) + (j>>1);
        int c  = j & 1;
        if (kx < KK) v = w_off[(size_t)o*KDIM + c*KK2 + ky*KK + kx];
    }
    bw[e] = f2bf(v);
}

// ---------------- K1: channel mean+max reduce, 4-way channel split ----------------
__global__ __launch_bounds__(256) void k_reduce2(const float* __restrict__ x, float* __restrict__ xc){
    __shared__ float4 ls[4][64];
    __shared__ float4 lm[4][64];
    const int tid = threadIdx.x;
    const int li = tid & 63;
    const int cq = tid >> 6;
    const int item = blockIdx.x*64 + li;
    const int b = item >> 12;
    const int hw4 = item & 4095;
    const float4* px = reinterpret_cast<const float4*>(x + (size_t)b*CH*IHW) + hw4;
    float4 s = {0.f,0.f,0.f,0.f};
    float4 m = {-3e38f,-3e38f,-3e38f,-3e38f};
    #pragma unroll 8
    for (int c=cq*64; c<cq*64+64; ++c){
        float4 v = px[(size_t)c*(IHW/4)];
        s.x+=v.x; s.y+=v.y; s.z+=v.z; s.w+=v.w;
        m.x=fmaxf(m.x,v.x); m.y=fmaxf(m.y,v.y); m.z=fmaxf(m.z,v.z); m.w=fmaxf(m.w,v.w);
    }
    ls[cq][li]=s; lm[cq][li]=m;
    __syncthreads();
    if (cq==0){
        #pragma unroll
        for (int q=1;q<4;++q){
            float4 s2 = ls[q][li], m2 = lm[q][li];
            s.x+=s2.x; s.y+=s2.y; s.z+=s2.z; s.w+=s2.w;
            m.x=fmaxf(m.x,m2.x); m.y=fmaxf(m.y,m2.y); m.z=fmaxf(m.z,m2.z); m.w=fmaxf(m.w,m2.w);
        }
        const float inv = 1.0f/(float)CH;
        float4 a = {s.x*inv, s.y*inv, s.z*inv, s.w*inv};
        float4* pxc = reinterpret_cast<float4*>(xc + (size_t)b*2*IHW) + hw4;
        pxc[0]     = a;
        pxc[IHW/4] = m;
    }
}

// ---------------- BN block-reduce helper ----------------
__device__ __forceinline__ void blockReduce2(float& s, float& q){
    #pragma unroll
    for (int o=32;o>0;o>>=1){ s += __shfl_down(s,o); q += __shfl_down(q,o); }
    __shared__ float ls[8], lq[8];
    int wid  = threadIdx.x >> 6;
    int lane = threadIdx.x & 63;
    if (lane==0){ ls[wid]=s; lq[wid]=q; }
    __syncthreads();
    if (threadIdx.x==0){
        int nw = blockDim.x >> 6;
        s = ls[0]; q = lq[0];
        for (int i=1;i<nw;++i){ s+=ls[i]; q+=lq[i]; }
    }
}

// ---------------- K2: fused MFMA conv + deformable sampling + BN partials ----------------
// One block = one image row (b,h). A-fragments built on the fly from packed row buffer P
// (no im2col). ks-outer MFMA loop keeps only 2 A-fragments live (low VGPR pressure).
__global__ __launch_bounds__(256,3) void k_dcn_fused(const float* __restrict__ xc,
    const unsigned short* __restrict__ bw, const float* __restrict__ b_off,
    const float* __restrict__ w_dcn, float* __restrict__ outp, float* __restrict__ partial)
{
    __shared__ __align__(16) unsigned char smem[52380];
    unsigned short* om = (unsigned short*)smem;          // [147][ASTR] u16 = 38808 B
    float* imgT = (float*)(smem + 38816);                // [2][9][128] f32 = 9216 B
    unsigned* P = (unsigned*)(smem + 48032);             // [7][PSTR] u32 = 3836 B (packed bf16 c0|c1)
    float* psum = (float*)(smem + 51868);                // [128] f32

    const int tid = threadIdx.x;
    const int bh = blockIdx.x;
    const int b  = bh >> 7;
    const int h  = bh & 127;
    const float* img = xc + (size_t)b*2*IHW;

    // phase 0a: stage 9 rows x 2 ch of xc into LDS (zero-filled outside image)
    for (int t = tid; t < 2*NROWS*32; t += 256){   // 576 float4 items
        int c   = t / (NROWS*32);
        int rem = t - c*(NROWS*32);
        int r   = rem >> 5;
        int x4  = rem & 31;
        int yy  = h - 4 + r;
        float4 v = {0.f,0.f,0.f,0.f};
        if ((unsigned)yy < (unsigned)IH)
            v = *reinterpret_cast<const float4*>(img + c*IHW + yy*IW + x4*4);
        *reinterpret_cast<float4*>(imgT + c*(NROWS*IW) + r*IW + x4*4) = v;
    }
    // phase 0b: packed conv-row buffer P[ky][p], p = x+3, x in [-3..131], rows h-3..h+3.
    for (int t = tid; t < 7*135; t += 256){
        int ky = t / 135;
        int p  = t - ky*135;
        int xx = p - 3;
        int yy = h - 3 + ky;
        unsigned pk = 0u;
        if (((unsigned)xx < (unsigned)IW) & ((unsigned)yy < (unsigned)IH)){
            int idx = yy*IW + xx;
            pk = (unsigned)f2bf(img[idx]) | ((unsigned)f2bf(img[IHW + idx]) << 16);
        }
        P[ky*PSTR + p] = pk;
    }
    __syncthreads();

    // phase 2: MFMA, ks-outer. A-fragment for m = ks*4+(lane>>4): 4 contiguous u32 from
    // P[ky=min(m>>1,6)][pix + 4*(m&1) ...]; m=14,15 read clamped row (B is zero there).
    const int wid  = tid >> 6;
    const int lane = tid & 63;
    const int l15  = lane & 15;
    const int lg   = lane >> 4;

    f32x4 acc[2][10];
    #pragma unroll
    for (int i=0;i<2;++i)
        #pragma unroll
        for (int j=0;j<10;++j) acc[i][j] = (f32x4){0.f,0.f,0.f,0.f};

    const bf16x8* bv = reinterpret_cast<const bf16x8*>(bw);
    #pragma unroll
    for (int ks=0; ks<4; ++ks){
        const int m = ks*4 + lg;
        int ky = m >> 1; ky = (ky > 6) ? 6 : ky;
        const int p0 = 4*(m & 1);
        bf16x8 af[2];
        #pragma unroll
        for (int mt=0; mt<2; ++mt){
            const int pix = wid*32 + mt*16 + l15;
            const unsigned* sp = P + ky*PSTR + pix + p0;
            union { unsigned u[4]; bf16x8 v; } uu;
            uu.u[0]=sp[0]; uu.u[1]=sp[1]; uu.u[2]=sp[2]; uu.u[3]=sp[3];
            af[mt] = uu.v;
        }
        #pragma unroll
        for (int nt=0; nt<10; ++nt){
            bf16x8 bfr = bv[(nt*4+ks)*64 + lane];
            acc[0][nt] = __builtin_amdgcn_mfma_f32_16x16x32_bf16(af[0], bfr, acc[0][nt], 0,0,0);
            acc[1][nt] = __builtin_amdgcn_mfma_f32_16x16x32_bf16(af[1], bfr, acc[1][nt], 0,0,0);
        }
    }
    // no barrier needed: om region untouched so far; P/imgT not written below

    // phase 3: f32 bias add, write om transposed (bf16 logits), b64-vectorized
    #pragma unroll
    for (int nt=0; nt<10; ++nt){
        const int cn = nt*16 + l15;
        if (cn < NCH){
            const float bo = b_off[cn];
            #pragma unroll
            for (int mt=0; mt<2; ++mt){
                const int pixb = wid*32 + mt*16 + lg*4;
                ushort4 wv;
                #pragma unroll
                for (int r=0; r<4; ++r){
                    reinterpret_cast<unsigned short*>(&wv)[r] = f2bf(acc[mt][nt][r] + bo);
                }
                *reinterpret_cast<ushort4*>(om + cn*ASTR + pixb) = wv;
            }
        }
    }
    __syncthreads();

    // phase 4: deformable sampling from LDS tile; 2 threads/pixel split taps
    const int pix  = tid & 127;
    const int half = tid >> 7;
    const int k0 = half ? 25 : 0;
    const int k1 = half ? 49 : 25;
    const float pixf = (float)pix;
    const unsigned short* omp = om + pix;
    int   kx    = half ? 4 : 0;
    float kyloc = half ? 4.f : 1.f;        // local row (tile base h-4): ky+1
    float kxm3  = (float)(kx - 3);
    int offO = 2*k0*ASTR;
    int offM = (KDIM + k0)*ASTR;
    float accv = 0.f;
    for (int k=k0; k<k1; ++k){
        float oy  = bf2f(omp[offO]);
        float ox  = bf2f(omp[offO + ASTR]);
        float msk = sigmoidf_(bf2f(omp[offM]));
        float yl = kyloc + oy;
        float xf = pixf + (kxm3 + ox);
        float y0f = floorf(yl), x0f = floorf(xf);
        float dy = yl - y0f, dx = xf - x0f;
        int t0 = (int)y0f, x0 = (int)x0f;
        int x1 = x0 + 1;
        float fx0 = ((unsigned)x0 < (unsigned)IW) ? 1.f : 0.f;
        float fx1 = ((unsigned)x1 < (unsigned)IW) ? 1.f : 0.f;
        int xc0 = min(max(x0,0),IW-1), xc1 = min(max(x1,0),IW-1);
        float w00=(1.f-dy)*(1.f-dx)*fx0;
        float w01=(1.f-dy)*dx      *fx1;
        float w10=dy*(1.f-dx)      *fx0;
        float w11=dy*dx            *fx1;
        float s0, s1;
        if ((unsigned)t0 < 8u){                  // both rows staged (zero-filled handles y-OOB)
            const float* q0 = imgT + t0*IW;
            const float* q1 = imgT + NROWS*IW + t0*IW;
            s0 = q0[xc0]*w00 + q0[xc1]*w01 + q0[IW+xc0]*w10 + q0[IW+xc1]*w11;
            s1 = q1[xc0]*w00 + q1[xc1]*w01 + q1[IW+xc0]*w10 + q1[IW+xc1]*w11;
        } else {                                 // rare: |oy| > ~4
            int y0g = t0 + h - 4;
            int y1g = y0g + 1;
            float fy0 = ((unsigned)y0g < (unsigned)IH) ? 1.f : 0.f;
            float fy1 = ((unsigned)y1g < (unsigned)IH) ? 1.f : 0.f;
            int yc0 = min(max(y0g,0),IH-1), yc1 = min(max(y1g,0),IH-1);
            int i00 = yc0*IW+xc0, i01 = yc0*IW+xc1, i10 = yc1*IW+xc0, i11 = yc1*IW+xc1;
            s0 = img[i00]*w00*fy0 + img[i01]*w01*fy0 + img[i10]*w10*fy1 + img[i11]*w11*fy1;
            s1 = img[IHW+i00]*w00*fy0 + img[IHW+i01]*w01*fy0 + img[IHW+i10]*w10*fy1 + img[IHW+i11]*w11*fy1;
        }
        accv += msk * (s0*w_dcn[k] + s1*w_dcn[KK2+k]);
        offO += 2*ASTR; offM += ASTR;
        ++kx; kxm3 += 1.f;
        if (kx == KK){ kx = 0; kxm3 = -3.f; kyloc += 1.f; }
    }
    if (half) psum[pix] = accv;
    __syncthreads();
    float o = 0.f;
    if (!half){ o = accv + psum[pix]; outp[bh*IW + pix] = o; }
    float s = o, q = o*o;
    blockReduce2(s,q);
    if (tid==0){ partial[bh] = s; partial[2048+bh] = q; }
}

// ---------------- K3: final stats from 2048 block partials ----------------
__global__ __launch_bounds__(256) void k_bn2(const float* __restrict__ partial, float* __restrict__ stats){
    const int tid = threadIdx.x;
    const float4* ps = reinterpret_cast<const float4*>(partial);
    const float4* pq = reinterpret_cast<const float4*>(partial + 2048);
    float s = 0.f, q = 0.f;
    for (int i = tid; i < 512; i += 256){
        float4 a = ps[i]; s += a.x+a.y+a.z+a.w;
        float4 c = pq[i]; q += c.x+c.y+c.z+c.w;
    }
    blockReduce2(s,q);
    if (tid==0){
        const float N = (float)(BATCH*IHW);
        float mean = s/N;
        float var  = fmaxf(q/N - mean*mean, 0.f);
        stats[0]=mean;
        stats[1]=rsqrtf(var + 1e-5f);
    }
}

__global__ __launch_bounds__(256) void k_final(const float* __restrict__ outp, const float* __restrict__ stats,
    const float* __restrict__ gamma, const float* __restrict__ beta, float* __restrict__ out){
    int t = blockIdx.x*256 + threadIdx.x;
    float mean = stats[0], istd = stats[1];
    float g = gamma[0], bt = beta[0];
    float4 v = reinterpret_cast<const float4*>(outp)[t];
    float4 r;
    r.x = sigmoidf_((v.x-mean)*istd*g + bt);
    r.y = sigmoidf_((v.y-mean)*istd*g + bt);
    r.z = sigmoidf_((v.z-mean)*istd*g + bt);
    r.w = sigmoidf_((v.w-mean)*istd*g + bt);
    reinterpret_cast<float4*>(out)[t] = r;
}

extern "C" void kernel_launch(void* const* d_in, const int* in_sizes, int n_in,
                              void* d_out, int out_size, void* d_ws, size_t ws_size,
                              hipStream_t stream){
    const float* x     = (const float*)d_in[0];
    const float* w_off = (const float*)d_in[1];
    const float* b_off = (const float*)d_in[2];
    const float* w_dcn = (const float*)d_in[3];
    const float* gamma = (const float*)d_in[4];
    const float* beta  = (const float*)d_in[5];
    float* ws = (float*)d_ws;
    float* xc      = ws;                                  // 524288 f32 (2 MB)
    float* outp    = ws + 524288;                         // 262144 f32 (1 MB)
    float* partial = ws + 786432;                         // 4096 f32 (sum | sumsq)
    float* stats   = partial + 4096;                      // 2 f32
    unsigned short* bw = (unsigned short*)(ws + 790544);  // 20480 u16 packed weights

    hipLaunchKernelGGL(k_pack,      dim3(80),   dim3(256), 0, stream, w_off, bw);
    hipLaunchKernelGGL(k_reduce2,   dim3(1024), dim3(256), 0, stream, x, xc);
    hipLaunchKernelGGL(k_dcn_fused, dim3(2048), dim3(256), 0, stream, xc, bw, b_off, w_dcn, outp, partial);
    hipLaunchKernelGGL(k_bn2,       dim3(1),    dim3(256), 0, stream, partial, stats);
    hipLaunchKernelGGL(k_final,     dim3(256),  dim3(256), 0, stream, outp, stats, gamma, beta, (float*)d_out);
}

// Round 3
// 112.883 us; speedup vs baseline: 1.4265x; 1.0296x over previous
//
#include <hip/hip_runtime.h>
#include <math.h>

#define BATCH 16
#define CH 256
#define IH 128
#define IW 128
#define IHW (IH*IW)
#define KK 7
#define KK2 49
#define NCH 147      // conv output channels (3*49)
#define KDIM 98      // 2 ch * 49 taps
#define OSTR 132     // omO row stride (u32); 132 % 32 == 4 -> uniform-min b128 writes
#define MSTR 132     // omM row stride (u16)
#define NROWS 9      // staged img rows h-4..h+4
#define PSTR 137     // P row stride (u32)

typedef __bf16 bf16x8 __attribute__((ext_vector_type(8)));
typedef float f32x4 __attribute__((ext_vector_type(4)));

__device__ __forceinline__ float sigmoidf_(float x){ return 1.0f/(1.0f+__expf(-x)); }
__device__ __forceinline__ unsigned short f2bf(float f){
    union{float f; unsigned u;} v; v.f=f;
    unsigned r = v.u + 0x7FFFu + ((v.u>>16)&1u);
    return (unsigned short)(r>>16);
}
__device__ __forceinline__ float bf2f(unsigned short u){
    union{unsigned u; float f;} v; v.u = ((unsigned)u)<<16; return v.f;
}

// ---------------- K0: pack weights into MFMA B-fragment order (bf16) ----------------
// Row mapping k' = m*8 + j; m = ks*4 + (lane>>4): m<14: ky=m>>1, kx=4*(m&1)+(j>>1), c=j&1;
// kx==7 and m>=14 are ZERO. Column mapping (pairs oy/ox onto the same lane):
//   nt 0..5: k = (nt>>1)*16 + l15 (0..47), o = 2k + (nt&1)
//   nt 6, l15==0: o=96 (oy48);  nt 7, l15==0: o=97 (ox48)
//   masks: nt6 l15>=1 -> o=98+(l15-1); nt7 l15>=1 -> o=98+14+l15;
//          nt8 -> o=98+30+l15; nt9 l15<3 -> o=98+46+l15; else ZERO
__global__ __launch_bounds__(256) void k_pack(const float* __restrict__ w_off,
                                              unsigned short* __restrict__ bw){
    int e = blockIdx.x*256 + threadIdx.x;      // 20480 elements
    int j    = e & 7;
    int lane = (e >> 3) & 63;
    int fs   = e >> 9;                          // 0..39
    int ks   = fs & 3;
    int nt   = fs >> 2;
    int l15  = lane & 15;
    int m    = ks*4 + (lane >> 4);
    int o = -1;
    if (nt < 6){
        int k = (nt>>1)*16 + l15;               // 0..47
        o = 2*k + (nt & 1);
    } else if (nt == 6){
        o = (l15==0) ? 96 : 98 + (l15-1);
    } else if (nt == 7){
        o = (l15==0) ? 97 : 98 + 14 + l15;
    } else if (nt == 8){
        o = 98 + 30 + l15;
    } else {
        o = (l15<3) ? 98 + 46 + l15 : -1;
    }
    float v = 0.f;
    if (o >= 0 && m < 14){
        int ky = m >> 1;
        int kx = 4*(m&1) + (j>>1);
        int c  = j & 1;
        if (kx < KK) v = w_off[(size_t)o*KDIM + c*KK2 + ky*KK + kx];
    }
    bw[e] = f2bf(v);
}

// ---------------- K1: channel mean+max reduce, 4-way channel split ----------------
__global__ __launch_bounds__(256) void k_reduce2(const float* __restrict__ x, float* __restrict__ xc){
    __shared__ float4 ls[4][64];
    __shared__ float4 lm[4][64];
    const int tid = threadIdx.x;
    const int li = tid & 63;
    const int cq = tid >> 6;
    const int item = blockIdx.x*64 + li;
    const int b = item >> 12;
    const int hw4 = item & 4095;
    const float4* px = reinterpret_cast<const float4*>(x + (size_t)b*CH*IHW) + hw4;
    float4 s = {0.f,0.f,0.f,0.f};
    float4 m = {-3e38f,-3e38f,-3e38f,-3e38f};
    #pragma unroll 8
    for (int c=cq*64; c<cq*64+64; ++c){
        float4 v = px[(size_t)c*(IHW/4)];
        s.x+=v.x; s.y+=v.y; s.z+=v.z; s.w+=v.w;
        m.x=fmaxf(m.x,v.x); m.y=fmaxf(m.y,v.y); m.z=fmaxf(m.z,v.z); m.w=fmaxf(m.w,v.w);
    }
    ls[cq][li]=s; lm[cq][li]=m;
    __syncthreads();
    if (cq==0){
        #pragma unroll
        for (int q=1;q<4;++q){
            float4 s2 = ls[q][li], m2 = lm[q][li];
            s.x+=s2.x; s.y+=s2.y; s.z+=s2.z; s.w+=s2.w;
            m.x=fmaxf(m.x,m2.x); m.y=fmaxf(m.y,m2.y); m.z=fmaxf(m.z,m2.z); m.w=fmaxf(m.w,m2.w);
        }
        const float inv = 1.0f/(float)CH;
        float4 a = {s.x*inv, s.y*inv, s.z*inv, s.w*inv};
        float4* pxc = reinterpret_cast<float4*>(xc + (size_t)b*2*IHW) + hw4;
        pxc[0]     = a;
        pxc[IHW/4] = m;
    }
}

// ---------------- BN block-reduce helper ----------------
__device__ __forceinline__ void blockReduce2(float& s, float& q){
    #pragma unroll
    for (int o=32;o>0;o>>=1){ s += __shfl_down(s,o); q += __shfl_down(q,o); }
    __shared__ float ls[8], lq[8];
    int wid  = threadIdx.x >> 6;
    int lane = threadIdx.x & 63;
    if (lane==0){ ls[wid]=s; lq[wid]=q; }
    __syncthreads();
    if (threadIdx.x==0){
        int nw = blockDim.x >> 6;
        s = ls[0]; q = lq[0];
        for (int i=1;i<nw;++i){ s+=ls[i]; q+=lq[i]; }
    }
}

// ---------------- K2: fused MFMA conv + deformable sampling + BN partials ----------------
// One block = one image row (b,h). omO[49][OSTR] u32 = packed (oy|ox) bf16 pair per tap;
// omM[49][MSTR] u16 = mask logits; imgT[9][128][2] channel-interleaved f32.
__global__ __launch_bounds__(256,3) void k_dcn_fused(const float* __restrict__ xc,
    const unsigned short* __restrict__ bw, const float* __restrict__ b_off,
    const float* __restrict__ w_dcn, float* __restrict__ outp, float* __restrict__ partial)
{
    __shared__ __align__(16) unsigned char smem[52380];
    unsigned*       omO = (unsigned*)smem;                  // [49][OSTR] u32 = 25872 B
    unsigned short* omM = (unsigned short*)(smem + 25872);  // [49][MSTR] u16 = 12936 B (pad 8)
    float* imgT = (float*)(smem + 38816);                   // [9][128][2] f32 = 9216 B
    unsigned* P = (unsigned*)(smem + 48032);                // [7][PSTR] u32 = 3836 B
    float* psum = (float*)(smem + 51868);                   // [128] f32

    const int tid = threadIdx.x;
    const int bh = blockIdx.x;
    const int b  = bh >> 7;
    const int h  = bh & 127;
    const float* img = xc + (size_t)b*2*IHW;

    // phase 0a: stage 9 rows of xc, channel-INTERLEAVED (zero-filled outside image)
    for (int t = tid; t < NROWS*32; t += 256){   // 288 items: 2 loads + 2 b128 stores
        int r  = t >> 5;
        int x4 = t & 31;
        int yy = h - 4 + r;
        float4 v0 = {0.f,0.f,0.f,0.f}, v1 = {0.f,0.f,0.f,0.f};
        if ((unsigned)yy < (unsigned)IH){
            v0 = *reinterpret_cast<const float4*>(img + yy*IW + x4*4);
            v1 = *reinterpret_cast<const float4*>(img + IHW + yy*IW + x4*4);
        }
        float4 w0 = {v0.x, v1.x, v0.y, v1.y};
        float4 w1 = {v0.z, v1.z, v0.w, v1.w};
        float4* dst = reinterpret_cast<float4*>(imgT + r*(IW*2) + x4*8);
        dst[0] = w0; dst[1] = w1;
    }
    // phase 0b: packed conv-row buffer P[ky][p], p = x+3, rows h-3..h+3
    for (int t = tid; t < 7*135; t += 256){
        int ky = t / 135;
        int p  = t - ky*135;
        int xx = p - 3;
        int yy = h - 3 + ky;
        unsigned pk = 0u;
        if (((unsigned)xx < (unsigned)IW) & ((unsigned)yy < (unsigned)IH)){
            int idx = yy*IW + xx;
            pk = (unsigned)f2bf(img[idx]) | ((unsigned)f2bf(img[IHW + idx]) << 16);
        }
        P[ky*PSTR + p] = pk;
    }
    __syncthreads();

    // phase 2: MFMA, ks-outer (2 A-frags live). A from P rows, B streamed from global.
    const int wid  = tid >> 6;
    const int lane = tid & 63;
    const int l15  = lane & 15;
    const int lg   = lane >> 4;

    f32x4 acc[2][10];
    #pragma unroll
    for (int i=0;i<2;++i)
        #pragma unroll
        for (int j=0;j<10;++j) acc[i][j] = (f32x4){0.f,0.f,0.f,0.f};

    const bf16x8* bv = reinterpret_cast<const bf16x8*>(bw);
    #pragma unroll
    for (int ks=0; ks<4; ++ks){
        const int m = ks*4 + lg;
        int ky = m >> 1; ky = (ky > 6) ? 6 : ky;
        const int p0 = 4*(m & 1);
        bf16x8 af[2];
        #pragma unroll
        for (int mt=0; mt<2; ++mt){
            const int pix = wid*32 + mt*16 + l15;
            const unsigned* sp = P + ky*PSTR + pix + p0;
            union { unsigned u[4]; bf16x8 v; } uu;
            uu.u[0]=sp[0]; uu.u[1]=sp[1]; uu.u[2]=sp[2]; uu.u[3]=sp[3];
            af[mt] = uu.v;
        }
        #pragma unroll
        for (int nt=0; nt<10; ++nt){
            bf16x8 bfr = bv[(nt*4+ks)*64 + lane];
            acc[0][nt] = __builtin_amdgcn_mfma_f32_16x16x32_bf16(af[0], bfr, acc[0][nt], 0,0,0);
            acc[1][nt] = __builtin_amdgcn_mfma_f32_16x16x32_bf16(af[1], bfr, acc[1][nt], 0,0,0);
        }
    }
    // no barrier needed: omO/omM untouched so far; P/imgT not written below

    // phase 3: bias add, pack (oy|ox) u32 pairs + mask logits, vectorized LDS writes
    #pragma unroll
    for (int g=0; g<3; ++g){                     // taps k = g*16 + l15 (0..47)
        const int k = g*16 + l15;
        float2 bo = *reinterpret_cast<const float2*>(b_off + 2*k);
        #pragma unroll
        for (int mt=0; mt<2; ++mt){
            const int pixb = wid*32 + mt*16 + lg*4;
            uint4 wv;
            #pragma unroll
            for (int r=0;r<4;++r){
                unsigned lo = f2bf(acc[mt][2*g  ][r] + bo.x);
                unsigned hi = f2bf(acc[mt][2*g+1][r] + bo.y);
                reinterpret_cast<unsigned*>(&wv)[r] = lo | (hi<<16);
            }
            *reinterpret_cast<uint4*>(omO + k*OSTR + pixb) = wv;
        }
    }
    if (l15 == 0){                               // tap k=48: cols 96 (nt6) / 97 (nt7)
        float2 bo = *reinterpret_cast<const float2*>(b_off + 96);
        #pragma unroll
        for (int mt=0; mt<2; ++mt){
            const int pixb = wid*32 + mt*16 + lg*4;
            uint4 wv;
            #pragma unroll
            for (int r=0;r<4;++r){
                unsigned lo = f2bf(acc[mt][6][r] + bo.x);
                unsigned hi = f2bf(acc[mt][7][r] + bo.y);
                reinterpret_cast<unsigned*>(&wv)[r] = lo | (hi<<16);
            }
            *reinterpret_cast<uint4*>(omO + 48*OSTR + pixb) = wv;
        }
    }
    #pragma unroll
    for (int nt=6; nt<10; ++nt){                 // mask logits
        int k; bool valid;
        if      (nt==6){ k = l15-1;  valid = (l15>=1); }
        else if (nt==7){ k = 14+l15; valid = (l15>=1); }
        else if (nt==8){ k = 30+l15; valid = true; }
        else           { k = 46+l15; valid = (l15<3); }
        if (valid){
            const float bo = b_off[KDIM + k];
            #pragma unroll
            for (int mt=0; mt<2; ++mt){
                const int pixb = wid*32 + mt*16 + lg*4;
                ushort4 wv;
                #pragma unroll
                for (int r=0;r<4;++r)
                    reinterpret_cast<unsigned short*>(&wv)[r] = f2bf(acc[mt][nt][r] + bo);
                *reinterpret_cast<ushort4*>(omM + k*MSTR + pixb) = wv;
            }
        }
    }
    __syncthreads();

    // phase 4: deformable sampling; 2 threads/pixel split taps; 6 LDS reads per tap
    const int pix  = tid & 127;
    const int half = tid >> 7;
    const int k0 = half ? 25 : 0;
    const int k1 = half ? 49 : 25;
    const float pixf = (float)pix;
    const unsigned* omOp = omO + pix;
    const unsigned short* omMp = omM + pix;
    const float2* imgT2 = reinterpret_cast<const float2*>(imgT);
    int   kx    = half ? 4 : 0;
    float kyloc = half ? 4.f : 1.f;        // local row (tile base h-4): ky+1
    float kxm3  = (float)(kx - 3);
    int offO = k0*OSTR;
    int offM = k0*MSTR;
    float accv = 0.f;
    for (int k=k0; k<k1; ++k){
        unsigned oyx = omOp[offO];
        float oy  = bf2f((unsigned short)(oyx & 0xFFFFu));
        float ox  = bf2f((unsigned short)(oyx >> 16));
        float msk = sigmoidf_(bf2f(omMp[offM]));
        float yl = kyloc + oy;
        float xf = pixf + (kxm3 + ox);
        float y0f = floorf(yl), x0f = floorf(xf);
        float dy = yl - y0f, dx = xf - x0f;
        int t0 = (int)y0f, x0 = (int)x0f;
        int x1 = x0 + 1;
        float fx0 = ((unsigned)x0 < (unsigned)IW) ? 1.f : 0.f;
        float fx1 = ((unsigned)x1 < (unsigned)IW) ? 1.f : 0.f;
        int xc0 = min(max(x0,0),IW-1), xc1 = min(max(x1,0),IW-1);
        float w00=(1.f-dy)*(1.f-dx)*fx0;
        float w01=(1.f-dy)*dx      *fx1;
        float w10=dy*(1.f-dx)      *fx0;
        float w11=dy*dx            *fx1;
        float s0, s1;
        if ((unsigned)t0 < 8u){                  // both rows staged (zero-filled handles y-OOB)
            const float2* q0 = imgT2 + t0*IW;
            float2 a00 = q0[xc0],    a01 = q0[xc1];
            float2 a10 = q0[IW+xc0], a11 = q0[IW+xc1];
            s0 = a00.x*w00 + a01.x*w01 + a10.x*w10 + a11.x*w11;
            s1 = a00.y*w00 + a01.y*w01 + a10.y*w10 + a11.y*w11;
        } else {                                 // rare: |oy| > ~4
            int y0g = t0 + h - 4;
            int y1g = y0g + 1;
            float fy0 = ((unsigned)y0g < (unsigned)IH) ? 1.f : 0.f;
            float fy1 = ((unsigned)y1g < (unsigned)IH) ? 1.f : 0.f;
            int yc0 = min(max(y0g,0),IH-1), yc1 = min(max(y1g,0),IH-1);
            int i00 = yc0*IW+xc0, i01 = yc0*IW+xc1, i10 = yc1*IW+xc0, i11 = yc1*IW+xc1;
            s0 = img[i00]*w00*fy0 + img[i01]*w01*fy0 + img[i10]*w10*fy1 + img[i11]*w11*fy1;
            s1 = img[IHW+i00]*w00*fy0 + img[IHW+i01]*w01*fy0 + img[IHW+i10]*w10*fy1 + img[IHW+i11]*w11*fy1;
        }
        accv += msk * (s0*w_dcn[k] + s1*w_dcn[KK2+k]);
        offO += OSTR; offM += MSTR;
        ++kx; kxm3 += 1.f;
        if (kx == KK){ kx = 0; kxm3 = -3.f; kyloc += 1.f; }
    }
    if (half) psum[pix] = accv;
    __syncthreads();
    float o = 0.f;
    if (!half){ o = accv + psum[pix]; outp[bh*IW + pix] = o; }
    float s = o, q = o*o;
    blockReduce2(s,q);
    if (tid==0){ partial[bh] = s; partial[2048+bh] = q; }
}

// ---------------- K3: final stats from 2048 block partials ----------------
__global__ __launch_bounds__(256) void k_bn2(const float* __restrict__ partial, float* __restrict__ stats){
    const int tid = threadIdx.x;
    const float4* ps = reinterpret_cast<const float4*>(partial);
    const float4* pq = reinterpret_cast<const float4*>(partial + 2048);
    float s = 0.f, q = 0.f;
    for (int i = tid; i < 512; i += 256){
        float4 a = ps[i]; s += a.x+a.y+a.z+a.w;
        float4 c = pq[i]; q += c.x+c.y+c.z+c.w;
    }
    blockReduce2(s,q);
    if (tid==0){
        const float N = (float)(BATCH*IHW);
        float mean = s/N;
        float var  = fmaxf(q/N - mean*mean, 0.f);
        stats[0]=mean;
        stats[1]=rsqrtf(var + 1e-5f);
    }
}

__global__ __launch_bounds__(256) void k_final(const float* __restrict__ outp, const float* __restrict__ stats,
    const float* __restrict__ gamma, const float* __restrict__ beta, float* __restrict__ out){
    int t = blockIdx.x*256 + threadIdx.x;
    float mean = stats[0], istd = stats[1];
    float g = gamma[0], bt = beta[0];
    float4 v = reinterpret_cast<const float4*>(outp)[t];
    float4 r;
    r.x = sigmoidf_((v.x-mean)*istd*g + bt);
    r.y = sigmoidf_((v.y-mean)*istd*g + bt);
    r.z = sigmoidf_((v.z-mean)*istd*g + bt);
    r.w = sigmoidf_((v.w-mean)*istd*g + bt);
    reinterpret_cast<float4*>(out)[t] = r;
}

extern "C" void kernel_launch(void* const* d_in, const int* in_sizes, int n_in,
                              void* d_out, int out_size, void* d_ws, size_t ws_size,
                              hipStream_t stream){
    const float* x     = (const float*)d_in[0];
    const float* w_off = (const float*)d_in[1];
    const float* b_off = (const float*)d_in[2];
    const float* w_dcn = (const float*)d_in[3];
    const float* gamma = (const float*)d_in[4];
    const float* beta  = (const float*)d_in[5];
    float* ws = (float*)d_ws;
    float* xc      = ws;                                  // 524288 f32 (2 MB)
    float* outp    = ws + 524288;                         // 262144 f32 (1 MB)
    float* partial = ws + 786432;                         // 4096 f32 (sum | sumsq)
    float* stats   = partial + 4096;                      // 2 f32
    unsigned short* bw = (unsigned short*)(ws + 790544);  // 20480 u16 packed weights

    hipLaunchKernelGGL(k_pack,      dim3(80),   dim3(256), 0, stream, w_off, bw);
    hipLaunchKernelGGL(k_reduce2,   dim3(1024), dim3(256), 0, stream, x, xc);
    hipLaunchKernelGGL(k_dcn_fused, dim3(2048), dim3(256), 0, stream, xc, bw, b_off, w_dcn, outp, partial);
    hipLaunchKernelGGL(k_bn2,       dim3(1),    dim3(256), 0, stream, partial, stats);
    hipLaunchKernelGGL(k_final,     dim3(256),  dim3(256), 0, stream, outp, stats, gamma, beta, (float*)d_out);
}